// Round 1
// baseline (204.950 us; speedup 1.0000x reference)
//
#include <hip/hip_runtime.h>

// Problem constants (fixed by the reference file)
#define BATCH   8
#define NVERT   50000
#define CIN     32
#define LSP     9
#define COUT    64
#define MVERT   12500
#define NNZ     37500

#define NFRAG   2304           // 9 s * 4 g * 64 lanes (B fragments)
#define OUTDW   (BATCH * MVERT * COUT)

#define TILE_T  128            // tasks per block (32 per wave, 2 M-tiles)
#define TPB     293            // ceil(37500/128)

#define PRE_BLOCKS   6250
#define PACK_BLOCKS  9
#define HISTA_BLOCKS 147

#define ROWCAP  96             // LDS row-aggregation capacity (24 KB)

typedef __attribute__((ext_vector_type(8))) short  short8;
typedef __attribute__((ext_vector_type(4))) float  floatx4;

static __device__ __forceinline__ unsigned short f2bf(float f) {
    union { float f; unsigned int u; } c; c.f = f;
    unsigned int u = c.u;
    return (unsigned short)((u + 0x7fffu + ((u >> 16) & 1u)) >> 16);
}

// ---- k1: precast x | pack W | hist atomics (hist pre-zeroed by memset)
__global__ __launch_bounds__(256)
void prep_kernel(const float* __restrict__ x, const float* __restrict__ w,
                 const int* __restrict__ rows,
                 unsigned short* __restrict__ x16, unsigned short* __restrict__ wp,
                 int* __restrict__ hist)
{
    const int blk = blockIdx.x;
    const int tid = threadIdx.x;
    if (blk < PRE_BLOCKS) {
        const size_t base = ((size_t)blk * 256 + tid) * 8;
        const float4* s = (const float4*)(x + base);
        float4 a = s[0], c = s[1];
        unsigned short t[8];
        t[0]=f2bf(a.x); t[1]=f2bf(a.y); t[2]=f2bf(a.z); t[3]=f2bf(a.w);
        t[4]=f2bf(c.x); t[5]=f2bf(c.y); t[6]=f2bf(c.z); t[7]=f2bf(c.w);
        *(uint4*)(x16 + base) = *(uint4*)t;
    } else if (blk < PRE_BLOCKS + PACK_BLOCKS) {
        // B-frag f=(s*4+g)*64+lane holds W[s*32+(lane>>4)*8+j][g*16+(lane&15)]
        const int f = (blk - PRE_BLOCKS) * 256 + tid;
        if (f < NFRAG) {
            int s = f >> 8, g = (f >> 6) & 3, lane = f & 63;
            int k0 = s * 32 + (lane >> 4) * 8, col = g * 16 + (lane & 15);
            unsigned short t[8];
            #pragma unroll
            for (int j = 0; j < 8; ++j)
                t[j] = f2bf(w[(size_t)(k0 + j) * COUT + col]);
            ((uint4*)wp)[f] = *(uint4*)t;
        }
    } else {
        const int z = (blk - PRE_BLOCKS - PACK_BLOCKS) * 256 + tid;
        if (z < NNZ) atomicAdd(&hist[rows[z]], 1);
    }
}

// ---- k2: exclusive scan of hist -> off2 (single block)
__global__ __launch_bounds__(1024)
void scan_kernel(const int* __restrict__ hist, int* __restrict__ off2) {
    __shared__ int sh[1024];
    const int t = threadIdx.x;
    const int base = t * 13;
    int loc[13];
    int s = 0;
    #pragma unroll
    for (int j = 0; j < 13; ++j) {
        int i = base + j;
        int v = (i < MVERT) ? hist[i] : 0;
        loc[j] = s; s += v;
    }
    sh[t] = s;
    __syncthreads();
    for (int d = 1; d < 1024; d <<= 1) {
        int v = (t >= d) ? sh[t - d] : 0;
        __syncthreads();
        sh[t] += v;
        __syncthreads();
    }
    const int excl = sh[t] - s;
    #pragma unroll
    for (int j = 0; j < 13; ++j) {
        int i = base + j;
        if (i < MVERT) off2[i] = excl + loc[j];
    }
}

// ---- k3: scatter into row-sorted order + build packed per-task spiral indices
__global__ __launch_bounds__(256)
void scatter_kernel(const int* __restrict__ rows, const int* __restrict__ cols,
                    const float* __restrict__ vals, const int* __restrict__ spiral,
                    int* __restrict__ off2,
                    int* __restrict__ rows_s, float* __restrict__ vals_s,
                    unsigned short* __restrict__ tidx) {
    int z = blockIdx.x * 256 + threadIdx.x;
    if (z < NNZ) {
        int r = rows[z];
        int c = cols[z];
        int pos = atomicAdd(&off2[r], 1);
        rows_s[pos] = r;
        vals_s[pos] = vals[z];
        unsigned short t[16];
        #pragma unroll
        for (int s = 0; s < 9; ++s) t[s] = (unsigned short)spiral[c * LSP + s];
        #pragma unroll
        for (int s = 9; s < 16; ++s) t[s] = 0;
        uint4* dst = (uint4*)(tidx + (size_t)pos * 16);
        dst[0] = *(uint4*)t;
        dst[1] = *(uint4*)(t + 8);
    }
}

// ---- k4: fused gather+GEMM+ELU+scale, LDS per-row aggregation, plain stores.
// Tasks are row-sorted, so a block's 128 tasks span a contiguous row range
// [first_row,last_row]. Rows strictly inside the range are owned exclusively
// by this block -> aggregated in LDS, written with plain coalesced float4
// stores. Only the two boundary rows (and >ROWCAP-span overflow, ~never) use
// global atomics. This removes the 9.5M global atomic RMWs that thrashed L2.
__global__ __launch_bounds__(256, 3)
void spiral_mfma7_kernel(const unsigned short* __restrict__ x16,
                         const unsigned short* __restrict__ wp,
                         const float* __restrict__ bias,
                         const unsigned short* __restrict__ tidx,
                         const int* __restrict__ rows_s,
                         const float* __restrict__ vals_s,
                         float* __restrict__ out)
{
    __shared__ float redu[ROWCAP * COUT];    // 24 KB

    const int bid  = blockIdx.x;
    const int b    = bid & 7;          // XCD swizzle: batch <-> XCD (x16/out L2-local)
    const int tile = bid >> 3;
    const int tid  = threadIdx.x;
    const int w    = tid >> 6;
    const int lane = tid & 63;
    const int quad = lane >> 4;
    const int m16  = lane & 15;
    const int z0w  = tile * TILE_T + 32 * w;   // wave's first sorted-task index

    // block row range (uniform -> scalar loads)
    const int z0        = tile * TILE_T;
    const int zl        = min(z0 + TILE_T - 1, NNZ - 1);
    const int first_row = rows_s[z0];
    const int last_row  = rows_s[zl];
    const int span      = last_row - first_row + 1;
    const int lim       = min(span, ROWCAP);

    // per-lane task metadata: lane L carries task z0w + (L&31) (coalesced)
    const int   zc   = min(z0w + (lane & 31), NNZ - 1);
    const int   rowv = rows_s[zc];
    const float valv = vals_s[zc];
    const uint4 p0 = *(const uint4*)(tidx + (size_t)zc * 16);
    const unsigned int p1 = *(const unsigned int*)(tidx + (size_t)zc * 16 + 8);
    int idx[9];
    idx[0] = p0.x & 0xffff;  idx[1] = p0.x >> 16;
    idx[2] = p0.y & 0xffff;  idx[3] = p0.y >> 16;
    idx[4] = p0.z & 0xffff;  idx[5] = p0.z >> 16;
    idx[6] = p0.w & 0xffff;  idx[7] = p0.w >> 16;
    idx[8] = p1 & 0xffff;

    const unsigned short* xb = x16 + (size_t)b * NVERT * CIN;

    // ---- all A-fragment gathers up front: one latency round-trip
    short8 A[2][9];
    #pragma unroll
    for (int s = 0; s < 9; ++s) {
        #pragma unroll
        for (int mt = 0; mt < 2; ++mt) {
            int tix = __shfl(idx[s], mt * 16 + m16);
            A[mt][s] = *(const short8*)(xb + (size_t)tix * CIN + quad * 8);
        }
    }

    // zero the LDS aggregation buffer while gathers are in flight
    for (int i = tid; i < lim * COUT; i += 256) redu[i] = 0.0f;
    __syncthreads();

    floatx4 acc[2][4];
    #pragma unroll
    for (int mt = 0; mt < 2; ++mt)
        #pragma unroll
        for (int g = 0; g < 4; ++g) acc[mt][g] = (floatx4){0.f, 0.f, 0.f, 0.f};

    #pragma unroll
    for (int s = 0; s < 9; ++s) {
        short8 bf[4];
        #pragma unroll
        for (int g = 0; g < 4; ++g)
            bf[g] = *(const short8*)(wp + (size_t)((s * 4 + g) * 64 + lane) * 8);
        #pragma unroll
        for (int mt = 0; mt < 2; ++mt)
            #pragma unroll
            for (int g = 0; g < 4; ++g)
                acc[mt][g] = __builtin_amdgcn_mfma_f32_16x16x32_bf16(A[mt][s], bf[g], acc[mt][g], 0, 0, 0);
    }

    // ---- epilogue: register run-compression, then LDS per-row aggregation
    float bs[4];
    #pragma unroll
    for (int g = 0; g < 4; ++g) bs[g] = bias[g * 16 + m16];
    float* outb = out + (size_t)b * MVERT * COUT;

    #pragma unroll
    for (int mt = 0; mt < 2; ++mt) {
        int   rr[4]; float vv[4]; bool val[4];
        #pragma unroll
        for (int r = 0; r < 4; ++r) {
            const int tsk = mt * 16 + quad * 4 + r;        // C row = quad*4 + reg
            rr[r]  = __shfl(rowv, tsk);
            vv[r]  = __shfl(valv, tsk);
            val[r] = (z0w + tsk) < NNZ;
        }
        bool emit[4];   // last element of an equal-row run
        #pragma unroll
        for (int r = 0; r < 4; ++r)
            emit[r] = (r == 3) || (!val[r + 1 > 3 ? 3 : r + 1]) || (rr[r + 1 > 3 ? 3 : r + 1] != rr[r]);
        #pragma unroll
        for (int g = 0; g < 4; ++g) {
            const int ch = g * 16 + m16;
            float s = 0.0f;
            #pragma unroll
            for (int r = 0; r < 4; ++r) {
                if (val[r]) {
                    float y = acc[mt][g][r] + bs[g];
                    y = (y > 0.0f) ? y : (__expf(y) - 1.0f);
                    s += y * vv[r];
                    if (emit[r]) {
                        const int local = rr[r] - first_row;
                        if (local < ROWCAP)
                            atomicAdd(&redu[local * COUT + ch], s);
                        else
                            atomicAdd(outb + (size_t)rr[r] * COUT + ch, s);
                        s = 0.0f;
                    }
                }
            }
        }
    }

    __syncthreads();

    // ---- store phase: interior rows plain float4 stores, boundary rows atomic
    for (int i = tid; i < lim * (COUT / 4); i += 256) {
        const int local = i >> 4;
        const int c4    = (i & 15) * 4;
        const int row   = first_row + local;
        const float4 v  = *(const float4*)(redu + local * COUT + c4);
        float* dst = outb + (size_t)row * COUT + c4;
        if (row == first_row || row == last_row) {
            atomicAdd(dst + 0, v.x);
            atomicAdd(dst + 1, v.y);
            atomicAdd(dst + 2, v.z);
            atomicAdd(dst + 3, v.w);
        } else {
            *(float4*)dst = v;
        }
    }
}

extern "C" void kernel_launch(void* const* d_in, const int* in_sizes, int n_in,
                              void* d_out, int out_size, void* d_ws, size_t ws_size,
                              hipStream_t stream) {
    const float* x      = (const float*)d_in[0];
    const float* w      = (const float*)d_in[1];
    const float* bias   = (const float*)d_in[2];
    const float* vals   = (const float*)d_in[3];
    const int*   spiral = (const int*)d_in[4];
    const int*   rows   = (const int*)d_in[5];
    const int*   cols   = (const int*)d_in[6];
    float* out = (float*)d_out;

    // ws layout
    char* base = (char*)d_ws;
    unsigned short* wp     = (unsigned short*)(base);                    //    36,864 B
    unsigned short* x16    = (unsigned short*)(base + 36864);            // 25,600,000 B
    int*            hist   = (int*)(base + 25636864);
    int*            off2   = (int*)(base + 25686864);
    int*            rows_s = (int*)(base + 25736864);
    float*          vals_s = (float*)(base + 26036896);
    unsigned short* tidx   = (unsigned short*)(base + 26186912);         //  1,200,000 B

    // zero hist (enables folding hist atomics into prep) and out (enables
    // plain interior stores + boundary atomics in the main kernel)
    hipMemsetAsync(hist, 0, MVERT * sizeof(int), stream);
    hipMemsetAsync(out, 0, (size_t)OUTDW * sizeof(float), stream);

    const int prep_grid = PRE_BLOCKS + PACK_BLOCKS + HISTA_BLOCKS;
    prep_kernel<<<prep_grid, 256, 0, stream>>>(x, w, rows, x16, wp, hist);
    scan_kernel<<<1, 1024, 0, stream>>>(hist, off2);
    scatter_kernel<<<147, 256, 0, stream>>>(rows, cols, vals, spiral, off2,
                                            rows_s, vals_s, tidx);
    spiral_mfma7_kernel<<<BATCH * TPB, 256, 0, stream>>>(x16, wp, bias, tidx,
                                                         rows_s, vals_s, out);
}

// Round 2
// 172.872 us; speedup vs baseline: 1.1856x; 1.1856x over previous
//
#include <hip/hip_runtime.h>

// Problem constants (fixed by the reference file)
#define BATCH   8
#define NVERT   50000
#define CIN     32
#define LSP     9
#define COUT    64
#define MVERT   12500
#define NNZ     37500

#define NFRAG   2304           // 9 s * 4 g * 64 lanes (B fragments)
#define OUTDW   (BATCH * MVERT * COUT)

#define TILE_T  128            // tasks per block (32 per wave, 2 M-tiles)
#define TPB     293            // ceil(37500/128)

#define PRE_BLOCKS   6250
#define PACK_BLOCKS  9
#define ZERO_BLOCKS  6250
#define HISTA_BLOCKS 147

typedef __attribute__((ext_vector_type(8))) short  short8;
typedef __attribute__((ext_vector_type(4))) float  floatx4;

static __device__ __forceinline__ unsigned short f2bf(float f) {
    union { float f; unsigned int u; } c; c.f = f;
    unsigned int u = c.u;
    return (unsigned short)((u + 0x7fffu + ((u >> 16) & 1u)) >> 16);
}

// ---- k1: precast x | pack W | zero out | hist atomics (hist pre-zeroed)
__global__ __launch_bounds__(256)
void prep_kernel(const float* __restrict__ x, const float* __restrict__ w,
                 const int* __restrict__ rows,
                 unsigned short* __restrict__ x16, unsigned short* __restrict__ wp,
                 float* __restrict__ out, int* __restrict__ hist)
{
    const int blk = blockIdx.x;
    const int tid = threadIdx.x;
    if (blk < PRE_BLOCKS) {
        const size_t base = ((size_t)blk * 256 + tid) * 8;
        const float4* s = (const float4*)(x + base);
        float4 a = s[0], c = s[1];
        unsigned short t[8];
        t[0]=f2bf(a.x); t[1]=f2bf(a.y); t[2]=f2bf(a.z); t[3]=f2bf(a.w);
        t[4]=f2bf(c.x); t[5]=f2bf(c.y); t[6]=f2bf(c.z); t[7]=f2bf(c.w);
        *(uint4*)(x16 + base) = *(uint4*)t;
    } else if (blk < PRE_BLOCKS + PACK_BLOCKS) {
        // B-frag f=(s*4+g)*64+lane holds W[s*32+(lane>>4)*8+j][g*16+(lane&15)]
        const int f = (blk - PRE_BLOCKS) * 256 + tid;
        if (f < NFRAG) {
            int s = f >> 8, g = (f >> 6) & 3, lane = f & 63;
            int k0 = s * 32 + (lane >> 4) * 8, col = g * 16 + (lane & 15);
            unsigned short t[8];
            #pragma unroll
            for (int j = 0; j < 8; ++j)
                t[j] = f2bf(w[(size_t)(k0 + j) * COUT + col]);
            ((uint4*)wp)[f] = *(uint4*)t;
        }
    } else if (blk < PRE_BLOCKS + PACK_BLOCKS + ZERO_BLOCKS) {
        const size_t base = ((size_t)(blk - PRE_BLOCKS - PACK_BLOCKS) * 256 + tid) * 4;
        if (base < OUTDW) *(uint4*)(out + base) = (uint4){0, 0, 0, 0};
    } else {
        const int z = (blk - PRE_BLOCKS - PACK_BLOCKS - ZERO_BLOCKS) * 256 + tid;
        if (z < NNZ) atomicAdd(&hist[rows[z]], 1);
    }
}

// ---- k2: exclusive scan of hist -> off2 (single block)
__global__ __launch_bounds__(1024)
void scan_kernel(const int* __restrict__ hist, int* __restrict__ off2) {
    __shared__ int sh[1024];
    const int t = threadIdx.x;
    const int base = t * 13;
    int loc[13];
    int s = 0;
    #pragma unroll
    for (int j = 0; j < 13; ++j) {
        int i = base + j;
        int v = (i < MVERT) ? hist[i] : 0;
        loc[j] = s; s += v;
    }
    sh[t] = s;
    __syncthreads();
    for (int d = 1; d < 1024; d <<= 1) {
        int v = (t >= d) ? sh[t - d] : 0;
        __syncthreads();
        sh[t] += v;
        __syncthreads();
    }
    const int excl = sh[t] - s;
    #pragma unroll
    for (int j = 0; j < 13; ++j) {
        int i = base + j;
        if (i < MVERT) off2[i] = excl + loc[j];
    }
}

// ---- k3: scatter into row-sorted order + build packed per-task spiral indices
__global__ __launch_bounds__(256)
void scatter_kernel(const int* __restrict__ rows, const int* __restrict__ cols,
                    const float* __restrict__ vals, const int* __restrict__ spiral,
                    int* __restrict__ off2,
                    int* __restrict__ rows_s, float* __restrict__ vals_s,
                    unsigned short* __restrict__ tidx) {
    int z = blockIdx.x * 256 + threadIdx.x;
    if (z < NNZ) {
        int r = rows[z];
        int c = cols[z];
        int pos = atomicAdd(&off2[r], 1);
        rows_s[pos] = r;
        vals_s[pos] = vals[z];
        unsigned short t[16];
        #pragma unroll
        for (int s = 0; s < 9; ++s) t[s] = (unsigned short)spiral[c * LSP + s];
        #pragma unroll
        for (int s = 9; s < 16; ++s) t[s] = 0;
        uint4* dst = (uint4*)(tidx + (size_t)pos * 16);
        dst[0] = *(uint4*)t;
        dst[1] = *(uint4*)(t + 8);
    }
}

// ---- k4: fused gather+GEMM+ELU+scale + register-aggregated scatter-add.
// Change vs round 0: the 36 KB packed-W fragment table is staged in LDS once
// per block (cooperative copy + 1 barrier) and read via ds_read_b128, instead
// of being re-streamed through L1 by every wave (576 L1 line-transactions per
// wave, and 36 KB > 32 KB L1 so it thrashed against the x16 gathers).
// Epilogue reverted to round-0 fire-and-forget global atomics (LDS-agg
// epilogue regressed: atomics were not the critical path).
__global__ __launch_bounds__(256, 2)
void spiral_mfma8_kernel(const unsigned short* __restrict__ x16,
                         const uint4* __restrict__ wp4,
                         const float* __restrict__ bias,
                         const unsigned short* __restrict__ tidx,
                         const int* __restrict__ rows_s,
                         const float* __restrict__ vals_s,
                         float* __restrict__ out)
{
    __shared__ uint4 wl[NFRAG];            // 36,864 B

    const int bid  = blockIdx.x;
    const int b    = bid & 7;          // XCD swizzle: batch <-> XCD (x16/out L2-local)
    const int tile = bid >> 3;
    const int tid  = threadIdx.x;
    const int w    = tid >> 6;
    const int lane = tid & 63;
    const int quad = lane >> 4;
    const int m16  = lane & 15;
    const int z0w  = tile * TILE_T + 32 * w;   // wave's first sorted-task index

    // cooperative W-fragment copy into LDS (2304 frags / 256 threads = 9 each)
    #pragma unroll
    for (int i = 0; i < 9; ++i)
        wl[i * 256 + tid] = wp4[i * 256 + tid];

    // per-lane task metadata: lane L carries task z0w + (L&31) (coalesced)
    const int   zc   = min(z0w + (lane & 31), NNZ - 1);
    const int   rowv = rows_s[zc];
    const float valv = vals_s[zc];
    const uint4 p0 = *(const uint4*)(tidx + (size_t)zc * 16);
    const unsigned int p1 = *(const unsigned int*)(tidx + (size_t)zc * 16 + 8);
    int idx[9];
    idx[0] = p0.x & 0xffff;  idx[1] = p0.x >> 16;
    idx[2] = p0.y & 0xffff;  idx[3] = p0.y >> 16;
    idx[4] = p0.z & 0xffff;  idx[5] = p0.z >> 16;
    idx[6] = p0.w & 0xffff;  idx[7] = p0.w >> 16;
    idx[8] = p1 & 0xffff;

    const unsigned short* xb = x16 + (size_t)b * NVERT * CIN;

    // ---- all A-fragment gathers up front: one latency round-trip
    short8 A[2][9];
    #pragma unroll
    for (int s = 0; s < 9; ++s) {
        #pragma unroll
        for (int mt = 0; mt < 2; ++mt) {
            int tix = __shfl(idx[s], mt * 16 + m16);
            A[mt][s] = *(const short8*)(xb + (size_t)tix * CIN + quad * 8);
        }
    }

    floatx4 acc[2][4];
    #pragma unroll
    for (int mt = 0; mt < 2; ++mt)
        #pragma unroll
        for (int g = 0; g < 4; ++g) acc[mt][g] = (floatx4){0.f, 0.f, 0.f, 0.f};

    __syncthreads();                        // wl ready

    const unsigned short* wls = (const unsigned short*)wl;
    #pragma unroll
    for (int s = 0; s < 9; ++s) {
        short8 bf[4];
        #pragma unroll
        for (int g = 0; g < 4; ++g)
            bf[g] = *(const short8*)(wls + (size_t)((s * 4 + g) * 64 + lane) * 8);
        #pragma unroll
        for (int mt = 0; mt < 2; ++mt)
            #pragma unroll
            for (int g = 0; g < 4; ++g)
                acc[mt][g] = __builtin_amdgcn_mfma_f32_16x16x32_bf16(A[mt][s], bf[g], acc[mt][g], 0, 0, 0);
    }

    // ---- epilogue: register run-compression over 4 consecutive sorted tasks
    float bs[4];
    #pragma unroll
    for (int g = 0; g < 4; ++g) bs[g] = bias[g * 16 + m16];
    float* outb = out + (size_t)b * MVERT * COUT;

    #pragma unroll
    for (int mt = 0; mt < 2; ++mt) {
        int   rr[4]; float vv[4]; bool val[4];
        #pragma unroll
        for (int r = 0; r < 4; ++r) {
            const int tsk = mt * 16 + quad * 4 + r;        // C row = quad*4 + reg
            rr[r]  = __shfl(rowv, tsk);
            vv[r]  = __shfl(valv, tsk);
            val[r] = (z0w + tsk) < NNZ;
        }
        bool emit[4];   // last element of an equal-row run
        #pragma unroll
        for (int r = 0; r < 4; ++r)
            emit[r] = (r == 3) || (!val[r + 1 > 3 ? 3 : r + 1]) || (rr[r + 1 > 3 ? 3 : r + 1] != rr[r]);
        #pragma unroll
        for (int g = 0; g < 4; ++g) {
            const int ch = g * 16 + m16;
            float s = 0.0f;
            #pragma unroll
            for (int r = 0; r < 4; ++r) {
                if (val[r]) {
                    float y = acc[mt][g][r] + bs[g];
                    y = (y > 0.0f) ? y : (__expf(y) - 1.0f);
                    s += y * vv[r];
                    if (emit[r]) {
                        atomicAdd(outb + (size_t)rr[r] * COUT + ch, s);
                        s = 0.0f;
                    }
                }
            }
        }
    }
}

extern "C" void kernel_launch(void* const* d_in, const int* in_sizes, int n_in,
                              void* d_out, int out_size, void* d_ws, size_t ws_size,
                              hipStream_t stream) {
    const float* x      = (const float*)d_in[0];
    const float* w      = (const float*)d_in[1];
    const float* bias   = (const float*)d_in[2];
    const float* vals   = (const float*)d_in[3];
    const int*   spiral = (const int*)d_in[4];
    const int*   rows   = (const int*)d_in[5];
    const int*   cols   = (const int*)d_in[6];
    float* out = (float*)d_out;

    // ws layout
    char* base = (char*)d_ws;
    unsigned short* wp     = (unsigned short*)(base);                    //    36,864 B
    unsigned short* x16    = (unsigned short*)(base + 36864);            // 25,600,000 B
    int*            hist   = (int*)(base + 25636864);
    int*            off2   = (int*)(base + 25686864);
    int*            rows_s = (int*)(base + 25736864);
    float*          vals_s = (float*)(base + 26036896);
    unsigned short* tidx   = (unsigned short*)(base + 26186912);         //  1,200,000 B

    // zero hist so its atomics can fold into prep
    hipMemsetAsync(hist, 0, MVERT * sizeof(int), stream);

    const int prep_grid = PRE_BLOCKS + PACK_BLOCKS + ZERO_BLOCKS + HISTA_BLOCKS;
    prep_kernel<<<prep_grid, 256, 0, stream>>>(x, w, rows, x16, wp, out, hist);
    scan_kernel<<<1, 1024, 0, stream>>>(hist, off2);
    scatter_kernel<<<147, 256, 0, stream>>>(rows, cols, vals, spiral, off2,
                                            rows_s, vals_s, tidx);
    spiral_mfma8_kernel<<<BATCH * TPB, 256, 0, stream>>>(x16, (const uint4*)wp,
                                                         bias, tidx,
                                                         rows_s, vals_s, out);
}